// Round 14
// baseline (34.690 us; speedup 1.0000x reference)
//
#include <hip/hip_runtime.h>
#include <hip/hip_bf16.h>

#define Bsz 2048
#define Dim 128
#define Nrows 4096

typedef float f32x4 __attribute__((ext_vector_type(4)));
typedef __bf16 bf16x8 __attribute__((ext_vector_type(8)));
typedef __bf16 bf16x4 __attribute__((ext_vector_type(4)));

// ws layout:
//   part  @ 0       : 4096*32*4 = 512 KiB (per (row,strip32) sum exp(S-2), diag excl)
//   w1p   @ 512K    : 16*128*4 = 8 KiB (diag-block partials of sum lab_j*u_j)
//   wallp @ 512K+8K : 8 KiB
//   rowC  @ 512K+16K: 1 KiB ; rowU @ +1 KiB

// K1: fused normalize + 256x256 macro-tile Gram. 256 blocks x 512 thr (1/CU).
// Block (ibk,jbk): normalizes the 256 i-rows and 256 j-rows it needs straight
// from z/z_aug (f32), writes bf16 into chunk-XOR-swizzled LDS, computes the
// tile with swapped-operand MFMA + rank-1 epilogue (exp-sum only, diag excl).
// Diagonal blocks (ibk==jbk, disjoint 256-row spans) also emit w1/wall partials.
__global__ __launch_bounds__(512, 2) void k_gram(const float* __restrict__ z,
                                                 const float* __restrict__ za,
                                                 const long long* __restrict__ labels,
                                                 float* __restrict__ part,
                                                 float* __restrict__ w1p,
                                                 float* __restrict__ wallp) {
    __shared__ __bf16 Ai[256 * 128];   // 64 KB: [row][16 chunks of 8 bf16]
    __shared__ __bf16 Aj[256 * 128];   // 64 KB; diag blocks: first 16 KB = f32 scratch

    const int ibk = blockIdx.x >> 4, jbk = blockIdx.x & 15;
    const bool diag = (ibk == jbk);
    const int ibase = ibk * 256, jbase = jbk * 256;
    const int w = threadIdx.x >> 6, lane = threadIdx.x & 63;
    const int wiq = w & 3, wjh = w >> 2;
    const int l15 = lane & 15, l4 = lane >> 4;
    const int half = lane >> 5, l32 = lane & 31;
    const int g = w * 2 + half;          // row-group 0..15 (16 rows per iteration)
    float* scr = reinterpret_cast<float*>(Aj);   // diag-only scratch [2][16][128]

    // ---- normalize + stage: 32 lanes per row (f32 row = 32 x 16 B)
    float a1[4] = {0.f, 0.f, 0.f, 0.f}, a0[4] = {0.f, 0.f, 0.f, 0.f};
    const int p = l32 >> 1;              // bf16 chunk 0..15
    #pragma unroll
    for (int it = 0; it < 16; it++) {
        const int rl = it * 16 + g;      // local row 0..255
        {
            const int r = ibase + rl;
            const float* src = (r < Bsz) ? (z + (size_t)r * Dim) : (za + (size_t)(r - Bsz) * Dim);
            f32x4 x = *reinterpret_cast<const f32x4*>(src + l32 * 4);
            float ss = x[0]*x[0] + x[1]*x[1] + x[2]*x[2] + x[3]*x[3];
            ss += __shfl_xor(ss, 1); ss += __shfl_xor(ss, 2); ss += __shfl_xor(ss, 4);
            ss += __shfl_xor(ss, 8); ss += __shfl_xor(ss, 16);
            const float sc = 1.0f / fmaxf(sqrtf(ss), 1e-12f);
            const float u0 = x[0]*sc, u1 = x[1]*sc, u2 = x[2]*sc, u3 = x[3]*sc;
            bf16x4 b4 = {(__bf16)u0, (__bf16)u1, (__bf16)u2, (__bf16)u3};
            *reinterpret_cast<bf16x4*>(Ai + (rl * 16 + (p ^ (rl & 7))) * 8 + (l32 & 1) * 4) = b4;
            if (diag) {
                const float lf = (labels[r & (Bsz - 1)] == 1) ? 1.f : 0.f;
                a0[0] += u0; a0[1] += u1; a0[2] += u2; a0[3] += u3;
                a1[0] = fmaf(lf, u0, a1[0]); a1[1] = fmaf(lf, u1, a1[1]);
                a1[2] = fmaf(lf, u2, a1[2]); a1[3] = fmaf(lf, u3, a1[3]);
            }
        }
        if (!diag) {
            const int r = jbase + rl;
            const float* src = (r < Bsz) ? (z + (size_t)r * Dim) : (za + (size_t)(r - Bsz) * Dim);
            f32x4 x = *reinterpret_cast<const f32x4*>(src + l32 * 4);
            float ss = x[0]*x[0] + x[1]*x[1] + x[2]*x[2] + x[3]*x[3];
            ss += __shfl_xor(ss, 1); ss += __shfl_xor(ss, 2); ss += __shfl_xor(ss, 4);
            ss += __shfl_xor(ss, 8); ss += __shfl_xor(ss, 16);
            const float sc = 1.0f / fmaxf(sqrtf(ss), 1e-12f);
            bf16x4 b4 = {(__bf16)(x[0]*sc), (__bf16)(x[1]*sc), (__bf16)(x[2]*sc), (__bf16)(x[3]*sc)};
            *reinterpret_cast<bf16x4*>(Aj + (rl * 16 + (p ^ (rl & 7))) * 8 + (l32 & 1) * 4) = b4;
        }
    }
    if (diag) {   // park per-group w-partials in scratch (Aj unused for panels)
        #pragma unroll
        for (int k2 = 0; k2 < 4; k2++) {
            scr[g * 128 + l32 * 4 + k2]        = a1[k2];
            scr[2048 + g * 128 + l32 * 4 + k2] = a0[k2];
        }
    }
    __syncthreads();

    // diag blocks: finish w1/wall partials (concurrent with compute below)
    if (diag && threadIdx.x < 256) {
        const int d = threadIdx.x & 127;
        const int which = threadIdx.x >> 7;
        float acc = 0.f;
        #pragma unroll
        for (int gg = 0; gg < 16; gg++) acc += scr[which * 2048 + gg * 128 + d];
        (which ? wallp : w1p)[ibk * 128 + d] = acc;
    }

    const __bf16* AjP = diag ? Ai : Aj;

    // ---- i-side b-frags from LDS, resident (4 i-tiles x 4 ks)
    bf16x8 b[4][4];
    #pragma unroll
    for (int bt = 0; bt < 4; bt++)
        #pragma unroll
        for (int ks = 0; ks < 4; ks++) {
            const int row = wiq * 64 + bt * 16 + l15;
            b[bt][ks] = *reinterpret_cast<const bf16x8*>(
                Ai + (row * 16 + ((ks * 4 + l4) ^ (row & 7))) * 8);
        }

    float dsum[4] = {0.f, 0.f, 0.f, 0.f};
    const float KE1 = 2.8853900817779268f;    // 2*log2(e)
    const float KE0 = -2.8853900817779268f;

    #pragma unroll
    for (int at = 0; at < 8; at++) {
        const int arow = wjh * 128 + at * 16 + l15;
        bf16x8 a[4];
        #pragma unroll
        for (int ks = 0; ks < 4; ks++)
            a[ks] = *reinterpret_cast<const bf16x8*>(
                AjP + (arow * 16 + ((ks * 4 + l4) ^ (arow & 7))) * 8);
        const int jt = jbase + wjh * 128 + at * 16;

        #pragma unroll
        for (int bt = 0; bt < 4; bt++) {
            f32x4 acc = {0.f, 0.f, 0.f, 0.f};
            #pragma unroll
            for (int ks = 0; ks < 4; ks++)
                acc = __builtin_amdgcn_mfma_f32_16x16x32_bf16(a[ks], b[bt][ks], acc, 0, 0, 0);
            const bool dg = (jt == ibase + wiq * 64 + bt * 16);   // tile holds diagonal
            #pragma unroll
            for (int q = 0; q < 4; q++) {
                float e = exp2f(fmaf(acc[q], KE1, KE0));          // exp(S_ij - 2)
                if (dg && (l15 == l4 * 4 + q)) e = 0.f;           // exclude j == i
                dsum[bt] += e;
            }
        }
    }

    // ---- collapse the 4 l4-groups (j-partition); i = l15 stays lane-local
    const int strip = jbk * 2 + wjh;
    #pragma unroll
    for (int bt = 0; bt < 4; bt++) {
        float v0 = dsum[bt];
        v0 += __shfl_xor(v0, 16);
        v0 += __shfl_xor(v0, 32);
        if (l4 == 0)
            part[(ibase + wiq * 64 + bt * 16 + l15) * 32 + strip] = v0;
    }
}

// K2: 256 blocks x 256 thr. Prologue: reduce 16 w-partials + inline c1.
// Per-row: re-normalize rows i/partner from z/za (bf16-round), strip-reduce part.
__global__ __launch_bounds__(256) void k_row(const float* __restrict__ z,
                                             const float* __restrict__ za,
                                             const long long* __restrict__ labels,
                                             const float* __restrict__ part,
                                             const float* __restrict__ w1p,
                                             const float* __restrict__ wallp,
                                             float* __restrict__ rowC,
                                             float* __restrict__ rowU) {
    __shared__ float sw1[128], sw0[128];
    __shared__ int ci[256];
    __shared__ int sc1v;
    const int t = threadIdx.x;
    if (t < 128) {
        float a = 0.f;
        #pragma unroll
        for (int gg = 0; gg < 16; gg++) a += w1p[gg * 128 + t];
        sw1[t] = a;
    } else {
        const int d = t - 128;
        float a = 0.f;
        #pragma unroll
        for (int gg = 0; gg < 16; gg++) a += wallp[gg * 128 + d];
        sw0[d] = a;
    }
    {
        int c = 0;
        #pragma unroll
        for (int k = 0; k < 8; k++) c += (int)labels[t * 8 + k];
        ci[t] = c;
    }
    __syncthreads();
    for (int s = 128; s > 0; s >>= 1) {
        if (t < s) ci[t] += ci[t + s];
        __syncthreads();
    }
    if (t == 0) sc1v = ci[0];
    __syncthreads();

    const int wid = t >> 6, lane = t & 63;
    const int ls = lane & 31;
    const int c1 = sc1v;
    const float w1a = sw1[2 * lane], w1b = sw1[2 * lane + 1];
    const float wa  = sw0[2 * lane], wb = sw0[2 * lane + 1];
    float cs = 0.f, us = 0.f;
    #pragma unroll
    for (int rr = 0; rr < 4; rr++) {
        const int i = blockIdx.x * 16 + wid * 4 + rr;
        const int partner = (i < Bsz) ? i + Bsz : i - Bsz;
        const float* si = (i < Bsz) ? (z + (size_t)i * Dim) : (za + (size_t)(i - Bsz) * Dim);
        const float* sp = (partner < Bsz) ? (z + (size_t)partner * Dim)
                                          : (za + (size_t)(partner - Bsz) * Dim);
        const float2 xi = reinterpret_cast<const float2*>(si)[lane];
        const float2 xp = reinterpret_cast<const float2*>(sp)[lane];
        float ssi = xi.x * xi.x + xi.y * xi.y;
        float ssp = xp.x * xp.x + xp.y * xp.y;
        #pragma unroll
        for (int m = 1; m < 64; m <<= 1) {
            ssi += __shfl_xor(ssi, m);
            ssp += __shfl_xor(ssp, m);
        }
        const float sci = 1.0f / fmaxf(sqrtf(ssi), 1e-12f);
        const float scp = 1.0f / fmaxf(sqrtf(ssp), 1e-12f);
        const float u0 = (float)(__bf16)(xi.x * sci), u1 = (float)(__bf16)(xi.y * sci);
        const float p0 = (float)(__bf16)(xp.x * scp), p1 = (float)(__bf16)(xp.y * scp);

        float dn = part[i * 32 + ls];     // halves duplicate -> 2x after 64-reduce
        float d1 = u0 * w1a + u1 * w1b;   // u . w1
        float da = u0 * wa + u1 * wb;     // u . wall
        float ds = u0 * u0 + u1 * u1;     // u . u  (= S_ii / 2)
        float dp = u0 * p0 + u1 * p1;     // u . partner
        #pragma unroll
        for (int m = 1; m < 64; m <<= 1) {
            dn += __shfl_xor(dn, m);
            d1 += __shfl_xor(d1, m);
            da += __shfl_xor(da, m);
            ds += __shfl_xor(ds, m);
            dp += __shfl_xor(dp, m);
        }
        if (lane == 0) {
            const long long lb = labels[i & (Bsz - 1)];
            // dn doubled: lnD = log(dn/2) + 2 = log(dn) + (2 - ln2)
            const float lnD = logf(dn) + 1.30685282f;
            const float uns = lnD - 2.0f * dp;
            const float cnt = 2.f * (float)((lb == 1) ? c1 : (Bsz - c1));
            const float sii = 2.f * ds;
            const float sumeq = ((lb == 1) ? 2.f * d1 : 2.f * (da - d1)) - sii;
            const float sup = lnD - sumeq / (cnt - 1.f);
            cs += (lb == 1) ? sup : uns;
            us += uns;
        }
    }
    __shared__ float wcs[4], wus[4];
    if (lane == 0) { wcs[wid] = cs; wus[wid] = us; }
    __syncthreads();
    if (t == 0) {
        rowC[blockIdx.x] = wcs[0] + wcs[1] + wcs[2] + wcs[3];
        rowU[blockIdx.x] = wus[0] + wus[1] + wus[2] + wus[3];
    }
}

// K3: combine 256 block results -> scalar loss (c1 recomputed inline)
__global__ __launch_bounds__(256) void k_comb(const float* __restrict__ rowC,
                                              const float* __restrict__ rowU,
                                              const long long* __restrict__ labels,
                                              float* __restrict__ out) {
    __shared__ float sc[256], su[256];
    __shared__ int ci[256];
    const int t = threadIdx.x;
    sc[t] = rowC[t];
    su[t] = rowU[t];
    {
        int c = 0;
        #pragma unroll
        for (int k = 0; k < 8; k++) c += (int)labels[t * 8 + k];
        ci[t] = c;
    }
    __syncthreads();
    for (int s = 128; s > 0; s >>= 1) {
        if (t < s) { sc[t] += sc[t + s]; su[t] += su[t + s]; ci[t] += ci[t + s]; }
        __syncthreads();
    }
    if (t == 0) out[0] = ((ci[0] > 0) ? sc[0] : su[0]) / (float)Nrows;
}

extern "C" void kernel_launch(void* const* d_in, const int* in_sizes, int n_in,
                              void* d_out, int out_size, void* d_ws, size_t ws_size,
                              hipStream_t stream) {
    const float* z  = (const float*)d_in[0];
    const float* za = (const float*)d_in[1];
    const long long* labels = (const long long*)d_in[2];

    char* ws = (char*)d_ws;
    float* part  = (float*)(ws);
    float* w1p   = (float*)(ws + (512u << 10));
    float* wallp = (float*)(ws + (512u << 10) + (8u << 10));
    float* rowC  = (float*)(ws + (512u << 10) + (16u << 10));
    float* rowU  = (float*)(ws + (512u << 10) + (17u << 10));
    float* out   = (float*)d_out;

    hipLaunchKernelGGL(k_gram, dim3(256), dim3(512), 0, stream, z, za, labels, part, w1p, wallp);
    hipLaunchKernelGGL(k_row,  dim3(256), dim3(256), 0, stream, z, za, labels, part, w1p, wallp, rowC, rowU);
    hipLaunchKernelGGL(k_comb, dim3(1),   dim3(256), 0, stream, rowC, rowU, labels, out);
}